// Round 12
// baseline (464.811 us; speedup 1.0000x reference)
//
#include <hip/hip_runtime.h>

typedef _Float16 f16;
typedef _Float16 f16x8 __attribute__((ext_vector_type(8)));
typedef float f32x4 __attribute__((ext_vector_type(4)));

#define MFMA16(a, b, c) __builtin_amdgcn_mfma_f32_16x16x32_f16(a, b, c, 0, 0, 0)

// LDS layout (byte offsets), 64 KiB total -> 2 blocks/CU (LDS-limited).
// Phase A: h0 panel [32][512] f16 @0 (32K), h1 [32][512] f16 @32768 (32K)
// Phase B: h2 [32][256] f16 @0 (16K), logits f32 [32][112] @16384 (ends 30720),
//          proj f32 [32][104] @32768 (dead-h1 region, zeroed after L3 barrier)
#define H0 0
#define H1 32768
#define H2 0
#define LGO 16384
#define PRO 32768
#define SMEM_BYTES 65536

// ---------------- prep: transpose-cast weights to f16 ----------------
__global__ void k_tr(const float* __restrict__ W, f16* __restrict__ Wt,
                     int K, int N, int lgKp) {
  int t = blockIdx.x * 256 + threadIdx.x;
  int n = t >> lgKp, k = t & ((1 << lgKp) - 1);
  float v = (k < K && n < N) ? W[k * N + n] : 0.f;
  Wt[t] = (f16)v;
}

// ---------------- fused MLP (f16) + C51 projection ----------------

// A from swizzled LDS, B (weights) from global. Plain loop — the compiler
// pipelines loads itself; manual double-buffering spilled (R10: 148 MB scratch).
template <int KSTEPS, int NT, int SBIN>
__device__ __forceinline__ void layer_f16(const char* sm, int inOff,
                                          const f16* __restrict__ wt, int ldw,
                                          int nbase, int kbase, int lr, int ls,
                                          f32x4 (&acc)[NT][2]) {
  const int xr = (lr & 7) << 4;
  const char* p0 = sm + inOff + lr * SBIN;
  const char* p1 = sm + inOff + (lr + 16) * SBIN;
  const f16* wb = wt + (size_t)(nbase + lr) * ldw + kbase + ls * 8;
#pragma unroll
  for (int ks = 0; ks < KSTEPS; ++ks) {
    int cb = (ks * 64 + ls * 16) ^ xr;
    f16x8 a0 = *(const f16x8*)(p0 + cb);
    f16x8 a1 = *(const f16x8*)(p1 + cb);
#pragma unroll
    for (int nt = 0; nt < NT; ++nt) {
      f16x8 b = *(const f16x8*)(wb + nt * 16 * ldw + ks * 32);
      acc[nt][0] = MFMA16(a0, b, acc[nt][0]);
      acc[nt][1] = MFMA16(a1, b, acc[nt][1]);
    }
  }
}

// bias + relu + f16 cast -> swizzled LDS
template <int NT>
__device__ __forceinline__ void epi_f16(char* sm, int outOff, int sbout,
                                        const float* __restrict__ bias, int nbias,
                                        int colbase, int lr, int ls,
                                        f32x4 (&acc)[NT][2]) {
#pragma unroll
  for (int nt = 0; nt < NT; ++nt) {
    float bv = bias[nbias + nt * 16 + lr];
    int cb = (colbase + nt * 16 + lr) * 2;
#pragma unroll
    for (int r = 0; r < 4; ++r) {
      int row = ls * 4 + r;
      int xr = (row & 7) << 4;
      int o0 = row * sbout + (cb ^ xr);
      int o1 = (row + 16) * sbout + (cb ^ xr);
      *(f16*)(sm + outOff + o0) = (f16)fmaxf(acc[nt][0][r] + bv, 0.f);
      *(f16*)(sm + outOff + o1) = (f16)fmaxf(acc[nt][1][r] + bv, 0.f);
    }
  }
}

__global__ __launch_bounds__(512, 2) void k_fused(
    const float* __restrict__ obs, const float* __restrict__ act,
    const f16* __restrict__ w0t, const f16* __restrict__ w1t,
    const f16* __restrict__ w2t, const f16* __restrict__ w3t,
    const float* __restrict__ b0p, const float* __restrict__ b1p,
    const float* __restrict__ b2p, const float* __restrict__ b3p,
    const float* __restrict__ rew, const float* __restrict__ boot,
    const float* __restrict__ disc, const float* __restrict__ qsup,
    float* __restrict__ out) {
  __shared__ __align__(16) char sm[SMEM_BYTES];
  const int tid = threadIdx.x;
  const int wv = tid >> 6, l = tid & 63;
  const int lr = l & 15, ls = l >> 4;
  const int r0 = blockIdx.x * 32;

  // ---- layer-1 A-fragments from f32 obs/act (cast f16) ----
  f16x8 xh[2][2];  // [row half][k step]
#pragma unroll
  for (int h = 0; h < 2; ++h) {
    int grow = r0 + h * 16 + lr;
    const float* ob = obs + (size_t)grow * 48;
    const float* ac = act + (size_t)grow * 12;
    float f[2][8];
#pragma unroll
    for (int i = 0; i < 8; ++i) f[0][i] = ob[ls * 8 + i];
    if (ls < 2) {
#pragma unroll
      for (int i = 0; i < 8; ++i) f[1][i] = ob[32 + ls * 8 + i];
    } else if (ls == 2) {
#pragma unroll
      for (int i = 0; i < 8; ++i) f[1][i] = ac[i];
    } else {
#pragma unroll
      for (int i = 0; i < 8; ++i) f[1][i] = (i < 4) ? ac[8 + i] : 0.f;
    }
#pragma unroll
    for (int k = 0; k < 2; ++k)
#pragma unroll
      for (int i = 0; i < 8; ++i) xh[h][k][i] = (f16)f[k][i];
  }

  // layer-1 panel p: N-cols [p*512, p*512+512) -> h0 (local cols 0..511)
  auto layer1_panel = [&](int p) {
#pragma unroll
    for (int nt = 0; nt < 4; ++nt) {
      int n0 = p * 512 + wv * 64 + nt * 16;
      const f16* b0 = w0t + (size_t)(n0 + lr) * 64 + ls * 8;
      f32x4 c0 = {0.f, 0.f, 0.f, 0.f}, c1 = {0.f, 0.f, 0.f, 0.f};
#pragma unroll
      for (int k = 0; k < 2; ++k) {
        f16x8 bh = *(const f16x8*)(b0 + k * 32);
        c0 = MFMA16(xh[0][k], bh, c0);
        c1 = MFMA16(xh[1][k], bh, c1);
      }
      float bv = b0p[n0 + lr];
      int cb = (wv * 64 + nt * 16 + lr) * 2;
#pragma unroll
      for (int r = 0; r < 4; ++r) {
        int row = ls * 4 + r;
        int xr2 = (row & 7) << 4;
        *(f16*)(sm + H0 + row * 1024 + (cb ^ xr2)) = (f16)fmaxf(c0[r] + bv, 0.f);
        *(f16*)(sm + H0 + (row + 16) * 1024 + (cb ^ xr2)) = (f16)fmaxf(c1[r] + bv, 0.f);
      }
    }
  };

  // ---- layers 1+2, K-panel pipelined (h1 acc in registers) ----
  f32x4 acc2[4][2];
#pragma unroll
  for (int nt = 0; nt < 4; ++nt)
    acc2[nt][0] = acc2[nt][1] = (f32x4){0.f, 0.f, 0.f, 0.f};

  layer1_panel(0);
  __syncthreads();
  layer_f16<16, 4, 1024>(sm, H0, w1t, 1024, wv * 64, 0, lr, ls, acc2);
  __syncthreads();
  layer1_panel(1);
  __syncthreads();
  layer_f16<16, 4, 1024>(sm, H0, w1t, 1024, wv * 64, 512, lr, ls, acc2);
  epi_f16<4>(sm, H1, 1024, b1p, wv * 64, wv * 64, lr, ls, acc2);
  __syncthreads();  // h0 reads done; h1 complete

  // ---- layer 3: K=512, N=256 -> h2 (reusing h0 region) ----
  f32x4 acc3[2][2];
#pragma unroll
  for (int nt = 0; nt < 2; ++nt)
    acc3[nt][0] = acc3[nt][1] = (f32x4){0.f, 0.f, 0.f, 0.f};
  layer_f16<16, 2, 1024>(sm, H1, w2t, 512, wv * 32, 0, lr, ls, acc3);
  epi_f16<2>(sm, H2, 512, b2p, wv * 32, wv * 32, lr, ls, acc3);
  __syncthreads();  // h1 reads done; h2 complete

  // zero projection bins (dead-h1 region; consumed after next barrier)
  for (int i = tid; i < 32 * 104; i += 512) ((float*)(sm + PRO))[i] = 0.f;

  // ---- layer 4: K=256, N=112 (7 tiles, waves 0..6) -> logits f32 ----
  if (wv < 7) {
    f32x4 acc4[1][2];
    acc4[0][0] = acc4[0][1] = (f32x4){0.f, 0.f, 0.f, 0.f};
    layer_f16<8, 1, 512>(sm, H2, w3t, 256, wv * 16, 0, lr, ls, acc4);
    int col = wv * 16 + lr;
    float bv = (col < 101) ? b3p[col] : 0.f;
    float* Lg = (float*)(sm + LGO);
#pragma unroll
    for (int r = 0; r < 4; ++r) {
      int row = ls * 4 + r;
      Lg[row * 112 + col] = acc4[0][0][r] + bv;
      Lg[(row + 16) * 112 + col] = acc4[0][1][r] + bv;
    }
  }
  __syncthreads();

  // ---- softmax (f32) + C51 projection (f32, reciprocal-multiply b) ----
  {
    int r = tid >> 4, s = tid & 15;
    int rg = r0 + r;
    const float* Lg = (const float*)(sm + LGO);
    float* Pr = (float*)(sm + PRO);
    float lv[7];
    float mx = -3.4e38f;
#pragma unroll
    for (int i = 0; i < 7; ++i) {
      int j = s + 16 * i;
      float x = (j < 101) ? Lg[r * 112 + j] : -3.4e38f;
      lv[i] = x;
      mx = fmaxf(mx, x);
    }
    mx = fmaxf(mx, __shfl_xor(mx, 1));
    mx = fmaxf(mx, __shfl_xor(mx, 2));
    mx = fmaxf(mx, __shfl_xor(mx, 4));
    mx = fmaxf(mx, __shfl_xor(mx, 8));
    float smv = 0.f;
#pragma unroll
    for (int i = 0; i < 7; ++i) {
      float e = expf(lv[i] - mx);
      lv[i] = e;
      if (s + 16 * i < 101) smv += e;
    }
    smv += __shfl_xor(smv, 1);
    smv += __shfl_xor(smv, 2);
    smv += __shfl_xor(smv, 4);
    smv += __shfl_xor(smv, 8);

    // Verified-match chain (R8): tz = rew + (boot*disc)*q, clip,
    // b = (tz - V_MIN) * 5.0f   [1/delta_z == 5.0 exactly]
    float rw = rew[rg];
    float bd = __fmul_rn(boot[rg], disc[rg]);
#pragma unroll
    for (int i = 0; i < 7; ++i) {
      int j = s + 16 * i;
      if (j < 101) {
        float p = __fdiv_rn(lv[i], smv);
        float tz = __fadd_rn(rw, __fmul_rn(bd, qsup[j]));
        tz = fminf(fmaxf(tz, -10.f), 10.f);
        float bb = __fmul_rn(__fsub_rn(tz, -10.f), 5.0f);
        float fl = floorf(bb), cu = ceilf(bb);
        int li = (int)fl, ui = (int)cu;
        int l2 = li, u2 = ui;
        if (li == ui) {
          if (ui > 0) l2 = li - 1;
          if (li < 100) u2 = ui + 1;
        }
        atomicAdd(&Pr[r * 104 + l2], __fmul_rn(p, __fsub_rn((float)u2, bb)));
        atomicAdd(&Pr[r * 104 + u2], __fmul_rn(p, __fsub_rn(bb, (float)l2)));
      }
    }
  }
  __syncthreads();

  for (int i = tid; i < 32 * 101; i += 512) {
    int r = i / 101, j = i - r * 101;
    out[(size_t)(r0 + r) * 101 + j] = ((const float*)(sm + PRO))[r * 104 + j];
  }
}

// ---------------- launch ----------------

extern "C" void kernel_launch(void* const* d_in, const int* in_sizes, int n_in,
                              void* d_out, int out_size, void* d_ws, size_t ws_size,
                              hipStream_t stream) {
  const float* obs  = (const float*)d_in[0];
  const float* act  = (const float*)d_in[1];
  const float* rew  = (const float*)d_in[2];
  const float* boot = (const float*)d_in[3];
  const float* disc = (const float*)d_in[4];
  const float* qsup = (const float*)d_in[5];
  const float* W0 = (const float*)d_in[6];  const float* b0 = (const float*)d_in[7];
  const float* W1 = (const float*)d_in[8];  const float* b1 = (const float*)d_in[9];
  const float* W2 = (const float*)d_in[10]; const float* b2 = (const float*)d_in[11];
  const float* W3 = (const float*)d_in[12]; const float* b3 = (const float*)d_in[13];

  char* ws = (char*)d_ws;
  f16* w0t = (f16*)(ws);             // [1024][64]  131072 B
  f16* w1t = (f16*)(ws + 131072);    // [512][1024] 1048576 B
  f16* w2t = (f16*)(ws + 1179648);   // [256][512]  262144 B
  f16* w3t = (f16*)(ws + 1441792);   // [112][256]  57344 B  (end 1499136)

  k_tr<<<256, 256, 0, stream>>>(W0, w0t, 60, 1024, 6);
  k_tr<<<2048, 256, 0, stream>>>(W1, w1t, 1024, 512, 10);
  k_tr<<<512, 256, 0, stream>>>(W2, w2t, 512, 256, 9);
  k_tr<<<112, 256, 0, stream>>>(W3, w3t, 256, 101, 8);

  k_fused<<<2048, 512, 0, stream>>>(obs, act, w0t, w1t, w2t, w3t,
                                    b0, b1, b2, b3,
                                    rew, boot, disc, qsup, (float*)d_out);
}

// Round 13
// 454.747 us; speedup vs baseline: 1.0221x; 1.0221x over previous
//
#include <hip/hip_runtime.h>

typedef _Float16 f16;
typedef _Float16 f16x8 __attribute__((ext_vector_type(8)));
typedef float f32x4 __attribute__((ext_vector_type(4)));

#define MFMA16(a, b, c) __builtin_amdgcn_mfma_f32_16x16x32_f16(a, b, c, 0, 0, 0)

// 32 KiB LDS arena, time-shared:
//  P1..P5: h0-panel / h1  [32][512] f16, stride 1024 B @0   (full 32K)
//  P7..P8: h2             [32][256] f16, stride  512 B @16384
//  P8..P9: logits f32     [32][112]              @0          (over dead h1)
//  P9+:    proj f32       [32][104]              @14336      (over dead h2)
#define HAS 0
#define H2S 16384
#define LGS 0
#define PRS 14336
#define SMEM_BYTES 32768

// ---------------- prep: transpose-cast weights to f16 ----------------
__global__ void k_tr(const float* __restrict__ W, f16* __restrict__ Wt,
                     int K, int N, int lgKp) {
  int t = blockIdx.x * 256 + threadIdx.x;
  int n = t >> lgKp, k = t & ((1 << lgKp) - 1);
  float v = (k < K && n < N) ? W[k * N + n] : 0.f;
  Wt[t] = (f16)v;
}

// ---------------- fused MLP (f16) + C51 projection ----------------

// A from swizzled LDS, B (weights) from global. Rolled loop (unroll 2):
// small code footprint, ~8 loads in flight per iteration.
template <int KSTEPS, int NT, int SBIN>
__device__ __forceinline__ void layer_f16(const char* sm, int inOff,
                                          const f16* __restrict__ wt, int ldw,
                                          int nbase, int kbase, int lr, int ls,
                                          f32x4 (&acc)[NT][2]) {
  const int xr = (lr & 7) << 4;
  const char* p0 = sm + inOff + lr * SBIN;
  const char* p1 = sm + inOff + (lr + 16) * SBIN;
  const f16* wb = wt + (size_t)(nbase + lr) * ldw + kbase + ls * 8;
#pragma unroll 2
  for (int ks = 0; ks < KSTEPS; ++ks) {
    int cb = (ks * 64 + ls * 16) ^ xr;
    f16x8 a0 = *(const f16x8*)(p0 + cb);
    f16x8 a1 = *(const f16x8*)(p1 + cb);
#pragma unroll
    for (int nt = 0; nt < NT; ++nt) {
      f16x8 b = *(const f16x8*)(wb + nt * 16 * ldw + ks * 32);
      acc[nt][0] = MFMA16(a0, b, acc[nt][0]);
      acc[nt][1] = MFMA16(a1, b, acc[nt][1]);
    }
  }
}

// bias + relu + f16 cast -> swizzled LDS
template <int NT>
__device__ __forceinline__ void epi_f16(char* sm, int outOff, int sbout,
                                        const float* __restrict__ bias, int nbias,
                                        int colbase, int lr, int ls,
                                        f32x4 (&acc)[NT][2]) {
#pragma unroll
  for (int nt = 0; nt < NT; ++nt) {
    float bv = bias[nbias + nt * 16 + lr];
    int cb = (colbase + nt * 16 + lr) * 2;
#pragma unroll
    for (int r = 0; r < 4; ++r) {
      int row = ls * 4 + r;
      int xr = (row & 7) << 4;
      int o0 = row * sbout + (cb ^ xr);
      int o1 = (row + 16) * sbout + (cb ^ xr);
      *(f16*)(sm + outOff + o0) = (f16)fmaxf(acc[nt][0][r] + bv, 0.f);
      *(f16*)(sm + outOff + o1) = (f16)fmaxf(acc[nt][1][r] + bv, 0.f);
    }
  }
}

__global__ __launch_bounds__(512, 3) void k_fused(
    const float* __restrict__ obs, const float* __restrict__ act,
    const f16* __restrict__ w0t, const f16* __restrict__ w1t,
    const f16* __restrict__ w2t, const f16* __restrict__ w3t,
    const float* __restrict__ b0p, const float* __restrict__ b1p,
    const float* __restrict__ b2p, const float* __restrict__ b3p,
    const float* __restrict__ rew, const float* __restrict__ boot,
    const float* __restrict__ disc, const float* __restrict__ qsup,
    float* __restrict__ out) {
  __shared__ __align__(16) char sm[SMEM_BYTES];
  const int tid = threadIdx.x;
  const int wv = tid >> 6, l = tid & 63;
  const int lr = l & 15, ls = l >> 4;
  const int r0 = blockIdx.x * 32;

  // layer-1 panel p: N-cols [p*512, p*512+512) -> arena (stride 1024).
  // xh loaded fresh each call (keeps it dead across layer-2 phases).
  auto layer1_panel = [&](int p) {
    f16x8 xh[2][2];
#pragma unroll
    for (int h = 0; h < 2; ++h) {
      int grow = r0 + h * 16 + lr;
      const float* ob = obs + (size_t)grow * 48;
      const float* ac = act + (size_t)grow * 12;
      float f[2][8];
#pragma unroll
      for (int i = 0; i < 8; ++i) f[0][i] = ob[ls * 8 + i];
      if (ls < 2) {
#pragma unroll
        for (int i = 0; i < 8; ++i) f[1][i] = ob[32 + ls * 8 + i];
      } else if (ls == 2) {
#pragma unroll
        for (int i = 0; i < 8; ++i) f[1][i] = ac[i];
      } else {
#pragma unroll
        for (int i = 0; i < 8; ++i) f[1][i] = (i < 4) ? ac[8 + i] : 0.f;
      }
#pragma unroll
      for (int k = 0; k < 2; ++k)
#pragma unroll
        for (int i = 0; i < 8; ++i) xh[h][k][i] = (f16)f[k][i];
    }
#pragma unroll
    for (int nt = 0; nt < 4; ++nt) {
      int n0 = p * 512 + wv * 64 + nt * 16;
      const f16* b0 = w0t + (size_t)(n0 + lr) * 64 + ls * 8;
      f32x4 c0 = {0.f, 0.f, 0.f, 0.f}, c1 = {0.f, 0.f, 0.f, 0.f};
#pragma unroll
      for (int k = 0; k < 2; ++k) {
        f16x8 bh = *(const f16x8*)(b0 + k * 32);
        c0 = MFMA16(xh[0][k], bh, c0);
        c1 = MFMA16(xh[1][k], bh, c1);
      }
      float bv = b0p[n0 + lr];
      int cb = (wv * 64 + nt * 16 + lr) * 2;
#pragma unroll
      for (int r = 0; r < 4; ++r) {
        int row = ls * 4 + r;
        int xr2 = (row & 7) << 4;
        *(f16*)(sm + HAS + row * 1024 + (cb ^ xr2)) = (f16)fmaxf(c0[r] + bv, 0.f);
        *(f16*)(sm + HAS + (row + 16) * 1024 + (cb ^ xr2)) = (f16)fmaxf(c1[r] + bv, 0.f);
      }
    }
  };

  // ---- layers 1+2, K-panel pipelined (h1 acc in registers) ----
  f32x4 acc2[4][2];
#pragma unroll
  for (int nt = 0; nt < 4; ++nt)
    acc2[nt][0] = acc2[nt][1] = (f32x4){0.f, 0.f, 0.f, 0.f};

  layer1_panel(0);
  __syncthreads();
  layer_f16<16, 4, 1024>(sm, HAS, w1t, 1024, wv * 64, 0, lr, ls, acc2);
  __syncthreads();  // panel0 reads done before overwrite
  layer1_panel(1);
  __syncthreads();
  layer_f16<16, 4, 1024>(sm, HAS, w1t, 1024, wv * 64, 512, lr, ls, acc2);
  __syncthreads();  // panel1 reads done before h1 overwrite
  epi_f16<4>(sm, HAS, 1024, b1p, wv * 64, wv * 64, lr, ls, acc2);
  __syncthreads();  // h1 complete

  // ---- layer 3: K=512, N=256 ----
  f32x4 acc3[2][2];
#pragma unroll
  for (int nt = 0; nt < 2; ++nt)
    acc3[nt][0] = acc3[nt][1] = (f32x4){0.f, 0.f, 0.f, 0.f};
  layer_f16<16, 2, 1024>(sm, HAS, w2t, 512, wv * 32, 0, lr, ls, acc3);
  __syncthreads();  // h1 reads done before h2 overwrite (upper half)
  epi_f16<2>(sm, H2S, 512, b2p, wv * 32, wv * 32, lr, ls, acc3);
  __syncthreads();  // h2 complete

  // ---- layer 4: K=256, N=112 (7 tiles, waves 0..6) -> logits @0 ----
  if (wv < 7) {
    f32x4 acc4[1][2];
    acc4[0][0] = acc4[0][1] = (f32x4){0.f, 0.f, 0.f, 0.f};
    layer_f16<8, 1, 512>(sm, H2S, w3t, 256, wv * 16, 0, lr, ls, acc4);
    int col = wv * 16 + lr;
    float bv = (col < 101) ? b3p[col] : 0.f;
    float* Lg = (float*)(sm + LGS);
#pragma unroll
    for (int r = 0; r < 4; ++r) {
      int row = ls * 4 + r;
      Lg[row * 112 + col] = acc4[0][0][r] + bv;
      Lg[(row + 16) * 112 + col] = acc4[0][1][r] + bv;
    }
  }
  __syncthreads();  // logits complete; h2 dead

  // zero projection bins (over dead h2)
  for (int i = tid; i < 32 * 104; i += 512) ((float*)(sm + PRS))[i] = 0.f;
  __syncthreads();

  // ---- softmax (f32) + C51 projection (f32, reciprocal-multiply b) ----
  {
    int r = tid >> 4, s = tid & 15;
    int rg = r0 + r;
    const float* Lg = (const float*)(sm + LGS);
    float* Pr = (float*)(sm + PRS);
    float lv[7];
    float mx = -3.4e38f;
#pragma unroll
    for (int i = 0; i < 7; ++i) {
      int j = s + 16 * i;
      float x = (j < 101) ? Lg[r * 112 + j] : -3.4e38f;
      lv[i] = x;
      mx = fmaxf(mx, x);
    }
    mx = fmaxf(mx, __shfl_xor(mx, 1));
    mx = fmaxf(mx, __shfl_xor(mx, 2));
    mx = fmaxf(mx, __shfl_xor(mx, 4));
    mx = fmaxf(mx, __shfl_xor(mx, 8));
    float smv = 0.f;
#pragma unroll
    for (int i = 0; i < 7; ++i) {
      float e = expf(lv[i] - mx);
      lv[i] = e;
      if (s + 16 * i < 101) smv += e;
    }
    smv += __shfl_xor(smv, 1);
    smv += __shfl_xor(smv, 2);
    smv += __shfl_xor(smv, 4);
    smv += __shfl_xor(smv, 8);

    // Verified-match chain (R8): tz = rew + (boot*disc)*q, clip,
    // b = (tz - V_MIN) * 5.0f   [1/delta_z == 5.0 exactly]
    float rw = rew[rg];
    float bd = __fmul_rn(boot[rg], disc[rg]);
#pragma unroll
    for (int i = 0; i < 7; ++i) {
      int j = s + 16 * i;
      if (j < 101) {
        float p = __fdiv_rn(lv[i], smv);
        float tz = __fadd_rn(rw, __fmul_rn(bd, qsup[j]));
        tz = fminf(fmaxf(tz, -10.f), 10.f);
        float bb = __fmul_rn(__fsub_rn(tz, -10.f), 5.0f);
        float fl = floorf(bb), cu = ceilf(bb);
        int li = (int)fl, ui = (int)cu;
        int l2 = li, u2 = ui;
        if (li == ui) {
          if (ui > 0) l2 = li - 1;
          if (li < 100) u2 = ui + 1;
        }
        atomicAdd(&Pr[r * 104 + l2], __fmul_rn(p, __fsub_rn((float)u2, bb)));
        atomicAdd(&Pr[r * 104 + u2], __fmul_rn(p, __fsub_rn(bb, (float)l2)));
      }
    }
  }
  __syncthreads();

  for (int i = tid; i < 32 * 101; i += 512) {
    int r = i / 101, j = i - r * 101;
    out[(size_t)(r0 + r) * 101 + j] = ((const float*)(sm + PRS))[r * 104 + j];
  }
}

// ---------------- launch ----------------

extern "C" void kernel_launch(void* const* d_in, const int* in_sizes, int n_in,
                              void* d_out, int out_size, void* d_ws, size_t ws_size,
                              hipStream_t stream) {
  const float* obs  = (const float*)d_in[0];
  const float* act  = (const float*)d_in[1];
  const float* rew  = (const float*)d_in[2];
  const float* boot = (const float*)d_in[3];
  const float* disc = (const float*)d_in[4];
  const float* qsup = (const float*)d_in[5];
  const float* W0 = (const float*)d_in[6];  const float* b0 = (const float*)d_in[7];
  const float* W1 = (const float*)d_in[8];  const float* b1 = (const float*)d_in[9];
  const float* W2 = (const float*)d_in[10]; const float* b2 = (const float*)d_in[11];
  const float* W3 = (const float*)d_in[12]; const float* b3 = (const float*)d_in[13];

  char* ws = (char*)d_ws;
  f16* w0t = (f16*)(ws);             // [1024][64]  131072 B
  f16* w1t = (f16*)(ws + 131072);    // [512][1024] 1048576 B
  f16* w2t = (f16*)(ws + 1179648);   // [256][512]  262144 B
  f16* w3t = (f16*)(ws + 1441792);   // [112][256]  57344 B  (end 1499136)

  k_tr<<<256, 256, 0, stream>>>(W0, w0t, 60, 1024, 6);
  k_tr<<<2048, 256, 0, stream>>>(W1, w1t, 1024, 512, 10);
  k_tr<<<512, 256, 0, stream>>>(W2, w2t, 512, 256, 9);
  k_tr<<<112, 256, 0, stream>>>(W3, w3t, 256, 101, 8);

  k_fused<<<2048, 512, 0, stream>>>(obs, act, w0t, w1t, w2t, w3t,
                                    b0, b1, b2, b3,
                                    rew, boot, disc, qsup, (float*)d_out);
}

// Round 14
// 247.602 us; speedup vs baseline: 1.8773x; 1.8366x over previous
//
#include <hip/hip_runtime.h>

typedef _Float16 f16;
typedef _Float16 f16x8 __attribute__((ext_vector_type(8)));
typedef float f32x4 __attribute__((ext_vector_type(4)));

#define MFMA16(a, b, c) __builtin_amdgcn_mfma_f32_16x16x32_f16(a, b, c, 0, 0, 0)

// M=128 per block, 512 threads (8 waves), 512 blocks.
// 128 KiB LDS arena, time-shared (offsets in bytes):
//   x    [128][64] f16  @114688 (16K)  alive: P0..last L1 panel
//   pan  [128][256] f16 @0      (64K)  h0 K-panel, stride 512
//   h1   [128][512] f16 @0     (128K)  stride 1024 (over pan+x, both dead)
//   h2   [128][256] f16 @0      (64K)  stride 512  (over h1 after full read)
//   log  [128][112] f32 @65536  (57K)  (over h1 upper half, dead)
//   proj [128][104] f32 @0      (53K)  (over h2 after L4 reads)
#define XOFF 114688
#define PAN 0
#define H1O 0
#define H2O 0
#define LGO 65536
#define PRO 0
#define SMEM_BYTES 131072

// ---------------- prep: transpose-cast weights to f16 ----------------
__global__ void k_tr(const float* __restrict__ W, f16* __restrict__ Wt,
                     int K, int N, int lgKp) {
  int t = blockIdx.x * 256 + threadIdx.x;
  int n = t >> lgKp, k = t & ((1 << lgKp) - 1);
  float v = (k < K && n < N) ? W[k * N + n] : 0.f;
  Wt[t] = (f16)v;
}

// ---------------- fused MLP (f16, M=128) + C51 projection ----------------

// 8 row-groups (m=0..7); A from swizzled LDS, B (weights) from global.
template <int KSTEPS, int NT, int SBIN>
__device__ __forceinline__ void layer8(const char* sm, int inOff,
                                       const f16* __restrict__ wt, int ldw,
                                       int nbase, int kbase, int lr, int ls,
                                       f32x4 (&acc)[NT][8]) {
  const int xr = (lr & 7) << 4;
  const char* pb = sm + inOff + lr * SBIN;
  const f16* wb = wt + (size_t)(nbase + lr) * ldw + kbase + ls * 8;
#pragma unroll 2
  for (int ks = 0; ks < KSTEPS; ++ks) {
    int cb = (ks * 64 + ls * 16) ^ xr;
    f16x8 a[8];
#pragma unroll
    for (int m = 0; m < 8; ++m)
      a[m] = *(const f16x8*)(pb + m * 16 * SBIN + cb);
#pragma unroll
    for (int nt = 0; nt < NT; ++nt) {
      f16x8 b = *(const f16x8*)(wb + nt * 16 * ldw + ks * 32);
#pragma unroll
      for (int m = 0; m < 8; ++m)
        acc[nt][m] = MFMA16(a[m], b, acc[nt][m]);
    }
  }
}

// bias + relu + f16 cast -> swizzled LDS (stride sbout bytes)
template <int NT>
__device__ __forceinline__ void epi8(char* sm, int outOff, int sbout,
                                     const float* __restrict__ bias, int nbias,
                                     int colbase, int lr, int ls,
                                     f32x4 (&acc)[NT][8]) {
#pragma unroll
  for (int nt = 0; nt < NT; ++nt) {
    float bv = bias[nbias + nt * 16 + lr];
    int cb = (colbase + nt * 16 + lr) * 2;
#pragma unroll
    for (int m = 0; m < 8; ++m)
#pragma unroll
      for (int r = 0; r < 4; ++r) {
        int row = m * 16 + ls * 4 + r;
        *(f16*)(sm + outOff + row * sbout + (cb ^ ((row & 7) << 4))) =
            (f16)fmaxf(acc[nt][m][r] + bv, 0.f);
      }
  }
}

__global__ __launch_bounds__(512, 1) void k_fused(
    const float* __restrict__ obs, const float* __restrict__ act,
    const f16* __restrict__ w0t, const f16* __restrict__ w1t,
    const f16* __restrict__ w2t, const f16* __restrict__ w3t,
    const float* __restrict__ b0p, const float* __restrict__ b1p,
    const float* __restrict__ b2p, const float* __restrict__ b3p,
    const float* __restrict__ rew, const float* __restrict__ boot,
    const float* __restrict__ disc, const float* __restrict__ qsup,
    float* __restrict__ out) {
  __shared__ __align__(16) char sm[SMEM_BYTES];
  const int tid = threadIdx.x;
  const int wv = tid >> 6, l = tid & 63;
  const int lr = l & 15, ls = l >> 4;
  const int r0 = blockIdx.x * 128;

  // ---- stage x = concat(obs,act,pad)[128][64] f16 into LDS (swizzled) ----
#pragma unroll
  for (int half = 0; half < 2; ++half) {
    int a = tid + half * 512;          // 1024 slots: row*8+group
    int row = a >> 3, g = a & 7;
    const float* ob = obs + (size_t)(r0 + row) * 48;
    const float* ac = act + (size_t)(r0 + row) * 12;
    float f[8];
    if (g < 6) {
#pragma unroll
      for (int i = 0; i < 8; ++i) f[i] = ob[g * 8 + i];
    } else if (g == 6) {
#pragma unroll
      for (int i = 0; i < 8; ++i) f[i] = ac[i];
    } else {
#pragma unroll
      for (int i = 0; i < 8; ++i) f[i] = (i < 4) ? ac[8 + i] : 0.f;
    }
    f16x8 h;
#pragma unroll
    for (int i = 0; i < 8; ++i) h[i] = (f16)f[i];
    *(f16x8*)(sm + XOFF + row * 128 + ((g * 16) ^ ((row & 7) << 4))) = h;
  }
  __syncthreads();

  // ---- layers 1+2 over 4 K-panels of 256 (h1 acc in registers) ----
  f32x4 acc2[4][8];
#pragma unroll
  for (int nt = 0; nt < 4; ++nt)
#pragma unroll
    for (int m = 0; m < 8; ++m) acc2[nt][m] = (f32x4){0.f, 0.f, 0.f, 0.f};

  const int xr = (lr & 7) << 4;
  for (int p = 0; p < 4; ++p) {
    // L1 panel: h0 cols [p*256, p*256+256) -> pan (panel-local cols, stride 512)
#pragma unroll
    for (int nt = 0; nt < 2; ++nt) {
      int n0g = p * 256 + wv * 32 + nt * 16;
      const f16* b0 = w0t + (size_t)(n0g + lr) * 64 + ls * 8;
      f16x8 bf0 = *(const f16x8*)(b0);
      f16x8 bf1 = *(const f16x8*)(b0 + 32);
      float bv = b0p[n0g + lr];
      int cb = (wv * 32 + nt * 16 + lr) * 2;
#pragma unroll
      for (int m = 0; m < 8; ++m) {
        const char* px = sm + XOFF + (m * 16 + lr) * 128;
        f16x8 a0 = *(const f16x8*)(px + ((ls * 16) ^ xr));
        f16x8 a1 = *(const f16x8*)(px + ((64 + ls * 16) ^ xr));
        f32x4 c = {0.f, 0.f, 0.f, 0.f};
        c = MFMA16(a0, bf0, c);
        c = MFMA16(a1, bf1, c);
#pragma unroll
        for (int r = 0; r < 4; ++r) {
          int row = m * 16 + ls * 4 + r;
          *(f16*)(sm + PAN + row * 512 + (cb ^ ((row & 7) << 4))) =
              (f16)fmaxf(c[r] + bv, 0.f);
        }
      }
    }
    __syncthreads();
    // L2 partial: acc2 += pan · w1t[:, p*256 .. p*256+256)
    layer8<8, 4, 512>(sm, PAN, w1t, 1024, wv * 64, p * 256, lr, ls, acc2);
    __syncthreads();  // pan rewritten next iter (or h1 epi next)
  }
  epi8<4>(sm, H1O, 1024, b1p, wv * 64, wv * 64, lr, ls, acc2);
  __syncthreads();  // h1 complete

  // ---- layer 3: K=512, N=256 ----
  f32x4 acc3[2][8];
#pragma unroll
  for (int nt = 0; nt < 2; ++nt)
#pragma unroll
    for (int m = 0; m < 8; ++m) acc3[nt][m] = (f32x4){0.f, 0.f, 0.f, 0.f};
  layer8<16, 2, 1024>(sm, H1O, w2t, 512, wv * 32, 0, lr, ls, acc3);
  __syncthreads();  // all h1 reads done
  epi8<2>(sm, H2O, 512, b2p, wv * 32, wv * 32, lr, ls, acc3);
  __syncthreads();  // h2 complete

  // ---- layer 4: K=256, N=112 (waves 0..6) -> logits f32 @LGO ----
  if (wv < 7) {
    f32x4 acc4[1][8];
#pragma unroll
    for (int m = 0; m < 8; ++m) acc4[0][m] = (f32x4){0.f, 0.f, 0.f, 0.f};
    layer8<8, 1, 512>(sm, H2O, w3t, 256, wv * 16, 0, lr, ls, acc4);
    int col = wv * 16 + lr;
    float bv = (col < 101) ? b3p[col] : 0.f;
    float* Lg = (float*)(sm + LGO);
#pragma unroll
    for (int m = 0; m < 8; ++m)
#pragma unroll
      for (int r = 0; r < 4; ++r) {
        int row = m * 16 + ls * 4 + r;
        Lg[row * 112 + col] = acc4[0][m][r] + bv;
      }
  }
  __syncthreads();  // logits complete; h2 dead

  // zero projection bins (over dead h2)
  for (int i = tid; i < 128 * 104; i += 512) ((float*)(sm + PRO))[i] = 0.f;
  __syncthreads();

  // ---- softmax (f32) + C51 projection; 4 threads per batch row ----
  {
    int r = tid >> 2, s = tid & 3;
    int rg = r0 + r;
    const float* Lg = (const float*)(sm + LGO);
    float* Pr = (float*)(sm + PRO);
    float lv[26];
    float mx = -3.4e38f;
#pragma unroll
    for (int i = 0; i < 26; ++i) {
      int j = s + 4 * i;
      float x = (j < 101) ? Lg[r * 112 + j] : -3.4e38f;
      lv[i] = x;
      mx = fmaxf(mx, x);
    }
    mx = fmaxf(mx, __shfl_xor(mx, 1));
    mx = fmaxf(mx, __shfl_xor(mx, 2));
    float smv = 0.f;
#pragma unroll
    for (int i = 0; i < 26; ++i) {
      float e = expf(lv[i] - mx);
      lv[i] = e;
      if (s + 4 * i < 101) smv += e;
    }
    smv += __shfl_xor(smv, 1);
    smv += __shfl_xor(smv, 2);

    // Verified-match chain (R8): tz = rew + (boot*disc)*q, clip,
    // b = (tz - V_MIN) * 5.0f   [1/delta_z == 5.0 exactly]
    float rw = rew[rg];
    float bd = __fmul_rn(boot[rg], disc[rg]);
#pragma unroll
    for (int i = 0; i < 26; ++i) {
      int j = s + 4 * i;
      if (j < 101) {
        float p = __fdiv_rn(lv[i], smv);
        float tz = __fadd_rn(rw, __fmul_rn(bd, qsup[j]));
        tz = fminf(fmaxf(tz, -10.f), 10.f);
        float bb = __fmul_rn(__fsub_rn(tz, -10.f), 5.0f);
        float fl = floorf(bb), cu = ceilf(bb);
        int li = (int)fl, ui = (int)cu;
        int l2 = li, u2 = ui;
        if (li == ui) {
          if (ui > 0) l2 = li - 1;
          if (li < 100) u2 = ui + 1;
        }
        atomicAdd(&Pr[r * 104 + l2], __fmul_rn(p, __fsub_rn((float)u2, bb)));
        atomicAdd(&Pr[r * 104 + u2], __fmul_rn(p, __fsub_rn(bb, (float)l2)));
      }
    }
  }
  __syncthreads();

  for (int i = tid; i < 128 * 101; i += 512) {
    int r = i / 101, j = i - r * 101;
    out[(size_t)(r0 + r) * 101 + j] = ((const float*)(sm + PRO))[r * 104 + j];
  }
}

// ---------------- launch ----------------

extern "C" void kernel_launch(void* const* d_in, const int* in_sizes, int n_in,
                              void* d_out, int out_size, void* d_ws, size_t ws_size,
                              hipStream_t stream) {
  const float* obs  = (const float*)d_in[0];
  const float* act  = (const float*)d_in[1];
  const float* rew  = (const float*)d_in[2];
  const float* boot = (const float*)d_in[3];
  const float* disc = (const float*)d_in[4];
  const float* qsup = (const float*)d_in[5];
  const float* W0 = (const float*)d_in[6];  const float* b0 = (const float*)d_in[7];
  const float* W1 = (const float*)d_in[8];  const float* b1 = (const float*)d_in[9];
  const float* W2 = (const float*)d_in[10]; const float* b2 = (const float*)d_in[11];
  const float* W3 = (const float*)d_in[12]; const float* b3 = (const float*)d_in[13];

  char* ws = (char*)d_ws;
  f16* w0t = (f16*)(ws);             // [1024][64]  131072 B
  f16* w1t = (f16*)(ws + 131072);    // [512][1024] 1048576 B
  f16* w2t = (f16*)(ws + 1179648);   // [256][512]  262144 B
  f16* w3t = (f16*)(ws + 1441792);   // [112][256]  57344 B  (end 1499136)

  k_tr<<<256, 256, 0, stream>>>(W0, w0t, 60, 1024, 6);
  k_tr<<<2048, 256, 0, stream>>>(W1, w1t, 1024, 512, 10);
  k_tr<<<512, 256, 0, stream>>>(W2, w2t, 512, 256, 9);
  k_tr<<<112, 256, 0, stream>>>(W3, w3t, 256, 101, 8);

  k_fused<<<512, 512, 0, stream>>>(obs, act, w0t, w1t, w2t, w3t,
                                   b0, b1, b2, b3,
                                   rew, boot, disc, qsup, (float*)d_out);
}

// Round 15
// 232.091 us; speedup vs baseline: 2.0027x; 1.0668x over previous
//
#include <hip/hip_runtime.h>

typedef _Float16 f16;
typedef _Float16 f16x8 __attribute__((ext_vector_type(8)));
typedef float f32x4 __attribute__((ext_vector_type(4)));

#define MFMA16(a, b, c) __builtin_amdgcn_mfma_f32_16x16x32_f16(a, b, c, 0, 0, 0)

// M=128 per block, 512 threads (8 waves), 512 blocks.
// 128 KiB LDS arena, time-shared (offsets in bytes):
//   x    [128][64] f16  @114688 (16K)  alive: P0..last L1 panel
//   pan  [128][256] f16 @0      (64K)  h0 K-panel, stride 512
//   h1   [128][512] f16 @0     (128K)  stride 1024 (over pan+x, both dead)
//   h2   [128][256] f16 @0      (64K)  stride 512  (over h1 after full read)
//   log  [128][112] f32 @65536  (57K)  (over h1 upper half, dead)
//   proj [128][104] f32 @0      (53K)  (over h2 after L4 reads)
#define XOFF 114688
#define PAN 0
#define H1O 0
#define H2O 0
#define LGO 65536
#define PRO 0
#define SMEM_BYTES 131072

// ---------------- prep: transpose-cast weights to f16 ----------------
__global__ void k_tr(const float* __restrict__ W, f16* __restrict__ Wt,
                     int K, int N, int lgKp) {
  int t = blockIdx.x * 256 + threadIdx.x;
  int n = t >> lgKp, k = t & ((1 << lgKp) - 1);
  float v = (k < K && n < N) ? W[k * N + n] : 0.f;
  Wt[t] = (f16)v;
}

// ---------------- fused MLP (f16, M=128) + C51 projection ----------------

// 8 row-groups in two halves of 4 (lower A-fragment register pressure);
// A from swizzled LDS, B (weights) from global.
template <int KSTEPS, int NT, int SBIN>
__device__ __forceinline__ void layer8(const char* sm, int inOff,
                                       const f16* __restrict__ wt, int ldw,
                                       int nbase, int kbase, int lr, int ls,
                                       f32x4 (&acc)[NT][8]) {
  const int xr = (lr & 7) << 4;
  const char* pb = sm + inOff + lr * SBIN;
  const f16* wb = wt + (size_t)(nbase + lr) * ldw + kbase + ls * 8;
#pragma unroll 2
  for (int ks = 0; ks < KSTEPS; ++ks) {
    int cb = (ks * 64 + ls * 16) ^ xr;
    f16x8 b[NT];
#pragma unroll
    for (int nt = 0; nt < NT; ++nt)
      b[nt] = *(const f16x8*)(wb + nt * 16 * ldw + ks * 32);
#pragma unroll
    for (int mh = 0; mh < 2; ++mh) {
      f16x8 a[4];
#pragma unroll
      for (int q = 0; q < 4; ++q)
        a[q] = *(const f16x8*)(pb + (mh * 4 + q) * 16 * SBIN + cb);
#pragma unroll
      for (int nt = 0; nt < NT; ++nt)
#pragma unroll
        for (int q = 0; q < 4; ++q)
          acc[nt][mh * 4 + q] = MFMA16(a[q], b[nt], acc[nt][mh * 4 + q]);
    }
  }
}

// bias + relu + f16 cast -> swizzled LDS (stride sbout bytes)
template <int NT>
__device__ __forceinline__ void epi8(char* sm, int outOff, int sbout,
                                     const float* __restrict__ bias, int nbias,
                                     int colbase, int lr, int ls,
                                     f32x4 (&acc)[NT][8]) {
#pragma unroll
  for (int nt = 0; nt < NT; ++nt) {
    float bv = bias[nbias + nt * 16 + lr];
    int cb = (colbase + nt * 16 + lr) * 2;
#pragma unroll
    for (int m = 0; m < 8; ++m)
#pragma unroll
      for (int r = 0; r < 4; ++r) {
        int row = m * 16 + ls * 4 + r;
        *(f16*)(sm + outOff + row * sbout + (cb ^ ((row & 7) << 4))) =
            (f16)fmaxf(acc[nt][m][r] + bv, 0.f);
      }
  }
}

__global__ __launch_bounds__(512, 2) void k_fused(
    const float* __restrict__ obs, const float* __restrict__ act,
    const f16* __restrict__ w0t, const f16* __restrict__ w1t,
    const f16* __restrict__ w2t, const f16* __restrict__ w3t,
    const float* __restrict__ b0p, const float* __restrict__ b1p,
    const float* __restrict__ b2p, const float* __restrict__ b3p,
    const float* __restrict__ rew, const float* __restrict__ boot,
    const float* __restrict__ disc, const float* __restrict__ qsup,
    float* __restrict__ out) {
  __shared__ __align__(16) char sm[SMEM_BYTES];
  const int tid = threadIdx.x;
  const int wv = tid >> 6, l = tid & 63;
  const int lr = l & 15, ls = l >> 4;
  const int r0 = blockIdx.x * 128;

  // ---- stage x = concat(obs,act,pad)[128][64] f16 into LDS (swizzled) ----
#pragma unroll
  for (int half = 0; half < 2; ++half) {
    int a = tid + half * 512;          // 1024 slots: row*8+group
    int row = a >> 3, g = a & 7;
    const float* ob = obs + (size_t)(r0 + row) * 48;
    const float* ac = act + (size_t)(r0 + row) * 12;
    float f[8];
    if (g < 6) {
#pragma unroll
      for (int i = 0; i < 8; ++i) f[i] = ob[g * 8 + i];
    } else if (g == 6) {
#pragma unroll
      for (int i = 0; i < 8; ++i) f[i] = ac[i];
    } else {
#pragma unroll
      for (int i = 0; i < 8; ++i) f[i] = (i < 4) ? ac[8 + i] : 0.f;
    }
    f16x8 h;
#pragma unroll
    for (int i = 0; i < 8; ++i) h[i] = (f16)f[i];
    *(f16x8*)(sm + XOFF + row * 128 + ((g * 16) ^ ((row & 7) << 4))) = h;
  }
  __syncthreads();

  // ---- layers 1+2 over 4 K-panels of 256 (h1 acc in registers) ----
  f32x4 acc2[4][8];
#pragma unroll
  for (int nt = 0; nt < 4; ++nt)
#pragma unroll
    for (int m = 0; m < 8; ++m) acc2[nt][m] = (f32x4){0.f, 0.f, 0.f, 0.f};

  const int xr = (lr & 7) << 4;
  for (int p = 0; p < 4; ++p) {
    // L1 panel: h0 cols [p*256, p*256+256) -> pan (panel-local cols, stride 512)
#pragma unroll
    for (int nt = 0; nt < 2; ++nt) {
      int n0g = p * 256 + wv * 32 + nt * 16;
      const f16* b0 = w0t + (size_t)(n0g + lr) * 64 + ls * 8;
      f16x8 bf0 = *(const f16x8*)(b0);
      f16x8 bf1 = *(const f16x8*)(b0 + 32);
      float bv = b0p[n0g + lr];
      int cb = (wv * 32 + nt * 16 + lr) * 2;
#pragma unroll
      for (int m = 0; m < 8; ++m) {
        const char* px = sm + XOFF + (m * 16 + lr) * 128;
        f16x8 a0 = *(const f16x8*)(px + ((ls * 16) ^ xr));
        f16x8 a1 = *(const f16x8*)(px + ((64 + ls * 16) ^ xr));
        f32x4 c = {0.f, 0.f, 0.f, 0.f};
        c = MFMA16(a0, bf0, c);
        c = MFMA16(a1, bf1, c);
#pragma unroll
        for (int r = 0; r < 4; ++r) {
          int row = m * 16 + ls * 4 + r;
          *(f16*)(sm + PAN + row * 512 + (cb ^ ((row & 7) << 4))) =
              (f16)fmaxf(c[r] + bv, 0.f);
        }
      }
    }
    __syncthreads();
    // L2 partial: acc2 += pan · w1t[:, p*256 .. p*256+256)
    layer8<8, 4, 512>(sm, PAN, w1t, 1024, wv * 64, p * 256, lr, ls, acc2);
    __syncthreads();  // pan rewritten next iter (or h1 epi next)
  }
  epi8<4>(sm, H1O, 1024, b1p, wv * 64, wv * 64, lr, ls, acc2);
  __syncthreads();  // h1 complete

  // ---- layer 3: K=512, N=256 ----
  f32x4 acc3[2][8];
#pragma unroll
  for (int nt = 0; nt < 2; ++nt)
#pragma unroll
    for (int m = 0; m < 8; ++m) acc3[nt][m] = (f32x4){0.f, 0.f, 0.f, 0.f};
  layer8<16, 2, 1024>(sm, H1O, w2t, 512, wv * 32, 0, lr, ls, acc3);
  __syncthreads();  // all h1 reads done
  epi8<2>(sm, H2O, 512, b2p, wv * 32, wv * 32, lr, ls, acc3);
  __syncthreads();  // h2 complete

  // ---- layer 4: K=256, N=112 (waves 0..6) -> logits f32 @LGO ----
  if (wv < 7) {
    f32x4 acc4[1][8];
#pragma unroll
    for (int m = 0; m < 8; ++m) acc4[0][m] = (f32x4){0.f, 0.f, 0.f, 0.f};
    layer8<8, 1, 512>(sm, H2O, w3t, 256, wv * 16, 0, lr, ls, acc4);
    int col = wv * 16 + lr;
    float bv = (col < 101) ? b3p[col] : 0.f;
    float* Lg = (float*)(sm + LGO);
#pragma unroll
    for (int m = 0; m < 8; ++m)
#pragma unroll
      for (int r = 0; r < 4; ++r) {
        int row = m * 16 + ls * 4 + r;
        Lg[row * 112 + col] = acc4[0][m][r] + bv;
      }
  }
  __syncthreads();  // logits complete; h2 dead

  // zero projection bins (over dead h2)
  for (int i = tid; i < 128 * 104; i += 512) ((float*)(sm + PRO))[i] = 0.f;
  __syncthreads();

  // ---- softmax (f32) + C51 projection; 4 threads per batch row ----
  {
    int r = tid >> 2, s = tid & 3;
    int rg = r0 + r;
    const float* Lg = (const float*)(sm + LGO);
    float* Pr = (float*)(sm + PRO);
    float lv[26];
    float mx = -3.4e38f;
#pragma unroll
    for (int i = 0; i < 26; ++i) {
      int j = s + 4 * i;
      float x = (j < 101) ? Lg[r * 112 + j] : -3.4e38f;
      lv[i] = x;
      mx = fmaxf(mx, x);
    }
    mx = fmaxf(mx, __shfl_xor(mx, 1));
    mx = fmaxf(mx, __shfl_xor(mx, 2));
    float smv = 0.f;
#pragma unroll
    for (int i = 0; i < 26; ++i) {
      float e = expf(lv[i] - mx);
      lv[i] = e;
      if (s + 4 * i < 101) smv += e;
    }
    smv += __shfl_xor(smv, 1);
    smv += __shfl_xor(smv, 2);

    // Verified-match chain (R8): tz = rew + (boot*disc)*q, clip,
    // b = (tz - V_MIN) * 5.0f   [1/delta_z == 5.0 exactly]
    float rw = rew[rg];
    float bd = __fmul_rn(boot[rg], disc[rg]);
#pragma unroll
    for (int i = 0; i < 26; ++i) {
      int j = s + 4 * i;
      if (j < 101) {
        float p = __fdiv_rn(lv[i], smv);
        float tz = __fadd_rn(rw, __fmul_rn(bd, qsup[j]));
        tz = fminf(fmaxf(tz, -10.f), 10.f);
        float bb = __fmul_rn(__fsub_rn(tz, -10.f), 5.0f);
        float fl = floorf(bb), cu = ceilf(bb);
        int li = (int)fl, ui = (int)cu;
        int l2 = li, u2 = ui;
        if (li == ui) {
          if (ui > 0) l2 = li - 1;
          if (li < 100) u2 = ui + 1;
        }
        atomicAdd(&Pr[r * 104 + l2], __fmul_rn(p, __fsub_rn((float)u2, bb)));
        atomicAdd(&Pr[r * 104 + u2], __fmul_rn(p, __fsub_rn(bb, (float)l2)));
      }
    }
  }
  __syncthreads();

  for (int i = tid; i < 128 * 101; i += 512) {
    int r = i / 101, j = i - r * 101;
    out[(size_t)(r0 + r) * 101 + j] = ((const float*)(sm + PRO))[r * 104 + j];
  }
}

// ---------------- launch ----------------

extern "C" void kernel_launch(void* const* d_in, const int* in_sizes, int n_in,
                              void* d_out, int out_size, void* d_ws, size_t ws_size,
                              hipStream_t stream) {
  const float* obs  = (const float*)d_in[0];
  const float* act  = (const float*)d_in[1];
  const float* rew  = (const float*)d_in[2];
  const float* boot = (const float*)d_in[3];
  const float* disc = (const float*)d_in[4];
  const float* qsup = (const float*)d_in[5];
  const float* W0 = (const float*)d_in[6];  const float* b0 = (const float*)d_in[7];
  const float* W1 = (const float*)d_in[8];  const float* b1 = (const float*)d_in[9];
  const float* W2 = (const float*)d_in[10]; const float* b2 = (const float*)d_in[11];
  const float* W3 = (const float*)d_in[12]; const float* b3 = (const float*)d_in[13];

  char* ws = (char*)d_ws;
  f16* w0t = (f16*)(ws);             // [1024][64]  131072 B
  f16* w1t = (f16*)(ws + 131072);    // [512][1024] 1048576 B
  f16* w2t = (f16*)(ws + 1179648);   // [256][512]  262144 B
  f16* w3t = (f16*)(ws + 1441792);   // [112][256]  57344 B  (end 1499136)

  k_tr<<<256, 256, 0, stream>>>(W0, w0t, 60, 1024, 6);
  k_tr<<<2048, 256, 0, stream>>>(W1, w1t, 1024, 512, 10);
  k_tr<<<512, 256, 0, stream>>>(W2, w2t, 512, 256, 9);
  k_tr<<<112, 256, 0, stream>>>(W3, w3t, 256, 101, 8);

  k_fused<<<512, 512, 0, stream>>>(obs, act, w0t, w1t, w2t, w3t,
                                   b0, b1, b2, b3,
                                   rew, boot, disc, qsup, (float*)d_out);
}